// Round 10
// baseline (61.385 us; speedup 1.0000x reference)
//
#include <hip/hip_runtime.h>

// Problem constants (from reference setup_inputs)
#define BB 8
#define QQ 30
#define DD 1500
#define EE 768
#define KK 11
#define WW 736      // (1500-30)/2 + 1
#define WIN 30
#define STR 2

#define NW 18       // windows per block; d-span = 2*18+28 = 64 exactly
#define NWCH 41     // ceil(736/18)
#define SPAN 64
#define QSTR 398    // vf per-q stride (6*66 + 2): odd b64-slot stride across q
#define KSTR 66     // vf per-k stride (64 + 2)

typedef __attribute__((ext_vector_type(8))) __bf16 bf16x8;
typedef __attribute__((ext_vector_type(4))) float f32x4;
typedef __attribute__((ext_vector_type(4))) unsigned int uint4v;

__device__ inline unsigned int f2bf(float x) {   // f32 -> bf16 bits, RNE
    unsigned int u = __float_as_uint(x);
    return (u + 0x7fffu + ((u >> 16) & 1u)) >> 16;
}

__device__ inline void split8(const float4 va, const float4 vb,
                              bf16x8& bh, bf16x8& bl, float& ssq)
{
    float f[8] = {va.x, va.y, va.z, va.w, vb.x, vb.y, vb.z, vb.w};
    unsigned hu[8], lu[8];
    #pragma unroll
    for (int j = 0; j < 8; j++) {
        float x = f[j];
        ssq += x * x;
        unsigned h = f2bf(x);
        float hf = __uint_as_float(h << 16);
        unsigned l = f2bf(x - hf);
        hu[j] = h; lu[j] = l;
    }
    uint4v uh = {hu[0] | (hu[1] << 16), hu[2] | (hu[3] << 16),
                 hu[4] | (hu[5] << 16), hu[6] | (hu[7] << 16)};
    uint4v ul = {lu[0] | (lu[1] << 16), lu[2] | (lu[3] << 16),
                 lu[4] | (lu[5] << 16), lu[6] | (lu[7] << 16)};
    bh = __builtin_bit_cast(bf16x8, uh);
    bl = __builtin_bit_cast(bf16x8, ul);
}

#define MFMA(a, b, c) __builtin_amdgcn_mfma_f32_16x16x32_bf16(a, b, c, 0, 0, 0)

// ---------------------------------------------------------------------------
// Kernel 1: normalize q rows, split to bf16 hi/lo, pad to 32 rows (zeros)
// ---------------------------------------------------------------------------
__global__ __launch_bounds__(256) void skl_normq(
    const float* __restrict__ qe, ushort* __restrict__ qh, ushort* __restrict__ ql)
{
    int wid = threadIdx.x >> 6, lane = threadIdx.x & 63;
    int r = blockIdx.x * 4 + wid;        // 0..255 = b*32+q
    if (r >= BB * 32) return;
    int b = r >> 5, q = r & 31;
    ushort* ph = qh + (size_t)r * EE;
    ushort* pl = ql + (size_t)r * EE;
    if (q >= QQ) {
        #pragma unroll
        for (int k = 0; k < 3; k++) {
            int e = (lane + 64 * k) * 4;
            *(ushort4*)&ph[e] = make_ushort4(0, 0, 0, 0);
            *(ushort4*)&pl[e] = make_ushort4(0, 0, 0, 0);
        }
        return;
    }
    const float4* p = (const float4*)(qe + (size_t)(b * QQ + q) * EE);
    float4 v[3];
    float ss = 0.f;
    #pragma unroll
    for (int k = 0; k < 3; k++) {
        v[k] = p[lane + 64 * k];
        ss += v[k].x * v[k].x + v[k].y * v[k].y + v[k].z * v[k].z + v[k].w * v[k].w;
    }
    #pragma unroll
    for (int off = 32; off >= 1; off >>= 1) ss += __shfl_xor(ss, off);
    float inv = 1.f / fmaxf(sqrtf(ss), 1e-13f);
    #pragma unroll
    for (int k = 0; k < 3; k++) {
        float f[4] = {v[k].x * inv, v[k].y * inv, v[k].z * inv, v[k].w * inv};
        ushort hs[4], ls[4];
        #pragma unroll
        for (int j = 0; j < 4; j++) {
            unsigned h = f2bf(f[j]);
            float hf = __uint_as_float(h << 16);
            unsigned l = f2bf(f[j] - hf);
            hs[j] = (ushort)h; ls[j] = (ushort)l;
        }
        int e = (lane + 64 * k) * 4;
        *(ushort4*)&ph[e] = make_ushort4(hs[0], hs[1], hs[2], hs[3]);
        *(ushort4*)&pl[e] = make_ushort4(ls[0], ls[1], ls[2], ls[3]);
    }
}

// ---------------------------------------------------------------------------
// Kernel 2 (fused): MFMA cos (full K=768) -> invd (in-reg) -> RBF exps
// (2 k-passes via LDS vf) -> sliding window sums -> saturation -> pscore.
// Block: 30q x 64d (= 18 windows), 4 waves x 1 n-tile. grid = (41, 8).
// ---------------------------------------------------------------------------
__global__ __launch_bounds__(256) void skl_fused(
    const float* __restrict__ de,      // [8][1500][768]
    const ushort* __restrict__ qh,     // [8][32][768]
    const ushort* __restrict__ ql,
    const float* __restrict__ dmask,   // [8][1500]
    const float* __restrict__ qmask,   // [8][30]
    const float* __restrict__ qidfs,   // [240]
    const float* __restrict__ mu,      // [11]
    const float* __restrict__ sigma,   // [11]
    const float* __restrict__ w1, const float* __restrict__ b1,
    const float* __restrict__ w2, const float* __restrict__ b2,
    const float* __restrict__ w3, const float* __restrict__ b3,
    const float* __restrict__ dw,      // [11]
    float* __restrict__ pscore)        // [240][736]
{
    __shared__ float vf[QQ * QSTR];    // 30*398*4 = 46.6 KB
    __shared__ float dmv[SPAN];        // mask values
    __shared__ float dmf[SPAN];        // mask flags (0/1)

    int tid = threadIdx.x;
    int wave = tid >> 6, lane = tid & 63;
    int ln = lane & 15, g = lane >> 4;
    int wch = blockIdx.x, b = blockIdx.y;
    int w0 = wch * NW;
    int dbase = 2 * w0;
    int dl = 16 * wave + ln;           // this lane's local d (0..63)
    int d = dbase + dl;
    int dc = min(d, DD - 1);

    if (tid < SPAN) {
        int dd = dbase + tid;
        float m = (dd < DD) ? dmask[(size_t)b * DD + dd] : 0.f;
        dmv[tid] = m;
        dmf[tid] = (m != 0.f) ? 1.f : 0.f;
    }

    float muL[KK], i2s[KK], dwL[KK];
    #pragma unroll
    for (int k = 0; k < KK; k++) {
        muL[k] = mu[k];
        float s = sigma[k];
        i2s[k] = 1.f / (2.f * s * s);
        dwL[k] = dw[k];
    }

    const float* drow = de + ((size_t)b * DD + dc) * EE;
    const ushort* qhb = qh + (size_t)b * 32 * EE;
    const ushort* qlb = ql + (size_t)b * 32 * EE;

    f32x4 acc0 = {0.f, 0.f, 0.f, 0.f};
    f32x4 acc1 = {0.f, 0.f, 0.f, 0.f};
    float ssq = 0.f;

    #pragma unroll 6
    for (int kst = 0; kst < 24; kst++) {
        int e0 = 32 * kst + 8 * g;
        bf16x8 a0h = *(const bf16x8*)&qhb[(size_t)ln * EE + e0];
        bf16x8 a0l = *(const bf16x8*)&qlb[(size_t)ln * EE + e0];
        bf16x8 a1h = *(const bf16x8*)&qhb[(size_t)(16 + ln) * EE + e0];
        bf16x8 a1l = *(const bf16x8*)&qlb[(size_t)(16 + ln) * EE + e0];
        float4 va = *(const float4*)&drow[e0];
        float4 vb = *(const float4*)&drow[e0 + 4];
        bf16x8 bh, bl;
        split8(va, vb, bh, bl, ssq);
        acc0 = MFMA(a0h, bh, acc0);
        acc0 = MFMA(a0h, bl, acc0);
        acc0 = MFMA(a0l, bh, acc0);
        acc1 = MFMA(a1h, bh, acc1);
        acc1 = MFMA(a1h, bl, acc1);
        acc1 = MFMA(a1l, bh, acc1);
    }

    // full-row ssq: reduce over the 4 k-group lanes (xor 16, 32)
    ssq += __shfl_xor(ssq, 16);
    ssq += __shfl_xor(ssq, 32);
    float inv = 1.f / fmaxf(sqrtf(ssq), 1e-13f);

    // cos values this lane owns: C row = 4g+j, col = ln (m89 layout)
    float cosv[8];
    #pragma unroll
    for (int j = 0; j < 4; j++) {
        cosv[j]     = acc0[j] * inv;   // q = 4g+j
        cosv[4 + j] = acc1[j] * inv;   // q = 16+4g+j (if < 30)
    }

    __syncthreads();                   // dmv/dmf staged; vf writable
    float mval = dmv[dl];

    // task mapping: 180 tasks = 30 q x 6 window-triples
    bool isTask = (tid < QQ * 6);
    int tq = tid / 6, twt = tid % 6;
    int wl = 3 * twt;                  // local window base (covers wl..wl+2)
    int dw0 = 2 * wl;                  // first d of first window
    float pk[KK][3];
    float lenf[3];

    if (isTask) {
        float s = 0.f;
        #pragma unroll
        for (int j2 = 0; j2 < WIN / 2; j2++) {
            float2 v = *(const float2*)&dmf[dw0 + 2 * j2];
            s += v.x + v.y;
        }
        lenf[0] = s;
        s = s - (dmf[dw0] + dmf[dw0 + 1]) + (dmf[dw0 + 30] + dmf[dw0 + 31]);
        lenf[1] = s;
        s = s - (dmf[dw0 + 2] + dmf[dw0 + 3]) + (dmf[dw0 + 32] + dmf[dw0 + 33]);
        lenf[2] = s;
    }

    // ---- two k-passes over vf ----
    #pragma unroll
    for (int pass = 0; pass < 2; pass++) {
        int kb = pass * 6;
        int kn = pass ? 5 : 6;
        // write phase: each lane writes its (q, d) RBF values
        #pragma unroll
        for (int j = 0; j < 4; j++) {
            int q0 = 4 * g + j;
            float c0 = cosv[j];
            #pragma unroll
            for (int kk2 = 0; kk2 < 6; kk2++) {
                if (kk2 < kn) {
                    float diff = c0 - muL[kb + kk2];
                    vf[q0 * QSTR + kk2 * KSTR + dl] =
                        __expf(-diff * diff * i2s[kb + kk2]) * mval;
                }
            }
            int q1 = 16 + 4 * g + j;
            if (q1 < QQ) {
                float c1 = cosv[4 + j];
                #pragma unroll
                for (int kk2 = 0; kk2 < 6; kk2++) {
                    if (kk2 < kn) {
                        float diff = c1 - muL[kb + kk2];
                        vf[q1 * QSTR + kk2 * KSTR + dl] =
                            __expf(-diff * diff * i2s[kb + kk2]) * mval;
                    }
                }
            }
        }
        __syncthreads();
        // read phase: sliding 3-window sums per k
        if (isTask) {
            #pragma unroll
            for (int kk2 = 0; kk2 < 6; kk2++) {
                if (kk2 < kn) {
                    const float* vrow = &vf[tq * QSTR + kk2 * KSTR];
                    float s = 0.f;
                    #pragma unroll
                    for (int j2 = 0; j2 < WIN / 2; j2++) {
                        float2 v = *(const float2*)&vrow[dw0 + 2 * j2];
                        s += v.x + v.y;
                    }
                    pk[kb + kk2][0] = s;
                    s = s - (vrow[dw0] + vrow[dw0 + 1])
                          + (vrow[dw0 + 30] + vrow[dw0 + 31]);
                    pk[kb + kk2][1] = s;
                    s = s - (vrow[dw0 + 2] + vrow[dw0 + 3])
                          + (vrow[dw0 + 32] + vrow[dw0 + 33]);
                    pk[kb + kk2][2] = s;
                }
            }
        }
        __syncthreads();
    }

    // ---- finalize: saturation + dense_w, write pscore ----
    if (isTask) {
        int bq = b * QQ + tq;
        float idf = fmaxf(qidfs[bq], 0.f);
        float qm = qmask[bq];
        float w10 = w1[0], w11 = w1[1], bb1 = b1[0];
        float w20 = w2[0], w21 = w2[1], bb2 = b2[0];
        float w30 = w3[0], w31 = w3[1], bb3 = b3[0];
        #pragma unroll
        for (int wi = 0; wi < 3; wi++) {
            int w = w0 + wl + wi;
            if (w < WW) {
                float lf = lenf[wi];
                float sat1 = idf * w10 + lf * w11 + bb1;
                float sat2 = 1.f / (idf * w20 + lf * w21 + bb2);
                float sat3 = idf * w30 + lf * w31 + bb3;
                float mult = qm * (lf > 0.f ? 1.f : 0.f);
                float acc = 0.f;
                #pragma unroll
                for (int k = 0; k < KK; k++) {
                    float x = fmaxf(pk[k][wi], 1e-10f);
                    float p = exp2f(sat2 * __log2f(x));
                    acc += (sat1 * p - sat3) * dwL[k];
                }
                pscore[(size_t)bq * WW + w] = acc * mult;
            }
        }
    }
}

// ---------------------------------------------------------------------------
// Kernel 3: per batch: sum over q (256 threads), then single-wave top-3
// argmax + pooling + gather.
// ---------------------------------------------------------------------------
__global__ __launch_bounds__(256) void skl_topk(
    const float* __restrict__ pscore,  // [240][736]
    const float* __restrict__ chunk,   // [15]
    float* __restrict__ out)           // [8]
{
    __shared__ float s0[WW];
    int b = blockIdx.x;
    int tid = threadIdx.x;

    for (int w = tid; w < WW; w += 256) {
        float s = 0.f;
        for (int q = 0; q < QQ; q++) s += pscore[(size_t)(b * QQ + q) * WW + w];
        s0[w] = (s == 0.f) ? -9900.f : s;
    }
    __syncthreads();

    if (tid < 64) {
        int lane = tid;
        float m[12];
        #pragma unroll
        for (int r = 0; r < 12; r++) {
            int w = lane + 64 * r;
            m[r] = (w < WW) ? s0[w] : -3.3e38f;
        }

        int best[3];
        for (int c = 0; c < 3; c++) {
            float bv = -3.3e38f;
            int bi = 1 << 30;
            #pragma unroll
            for (int r = 0; r < 12; r++) {
                int w = lane + 64 * r;
                if (w < WW && m[r] > bv) { bv = m[r]; bi = w; }
            }
            #pragma unroll
            for (int off = 32; off >= 1; off >>= 1) {
                float ov = __shfl_down(bv, off);
                int oi = __shfl_down(bi, off);
                if (ov > bv || (ov == bv && oi < bi)) { bv = ov; bi = oi; }
            }
            bi = __shfl(bi, 0);
            best[c] = bi;
            float pen = -10001.f - (float)c;
            #pragma unroll
            for (int r = 0; r < 12; r++) {
                int w = lane + 64 * r;
                int dd = w - bi; if (dd < 0) dd = -dd;
                if (w < WW && dd < 15) m[r] = pen;
            }
        }

        float contrib = 0.f;
        if (lane < 15) {
            int c = lane % 3;
            int g = lane / 3;
            const int offs[5] = {0, -1, 1, -2, 2};
            int nb = best[c] + offs[g];
            nb = min(max(nb, 0), WW - 1);
            float v = s0[nb];
            if (v <= -9900.f) v = 0.f;
            contrib = v * chunk[lane];
        }
        #pragma unroll
        for (int off = 32; off >= 1; off >>= 1) contrib += __shfl_down(contrib, off);
        if (lane == 0) out[b] = contrib;
    }
}

// ---------------------------------------------------------------------------
extern "C" void kernel_launch(void* const* d_in, const int* in_sizes, int n_in,
                              void* d_out, int out_size, void* d_ws, size_t ws_size,
                              hipStream_t stream) {
    const float* qe    = (const float*)d_in[0];   // (8,30,768)
    const float* de    = (const float*)d_in[1];   // (8,1500,768)
    const float* qmask = (const float*)d_in[2];   // (8,30)
    const float* dmask = (const float*)d_in[3];   // (8,1500)
    const float* qidfs = (const float*)d_in[4];   // (8,30,1)
    // d_in[5] = document_idfs (unused by reference)
    const float* mu    = (const float*)d_in[6];   // (11,)
    const float* sigma = (const float*)d_in[7];   // (11,)
    const float* w1    = (const float*)d_in[8];
    const float* b1    = (const float*)d_in[9];
    const float* w2    = (const float*)d_in[10];
    const float* b2    = (const float*)d_in[11];
    const float* w3    = (const float*)d_in[12];
    const float* b3    = (const float*)d_in[13];
    const float* dw    = (const float*)d_in[14];  // (1,11)
    const float* chunk = (const float*)d_in[15];  // (1,15)
    float* out = (float*)d_out;

    float* ws = (float*)d_ws;
    float* pscore = ws;                        // 240*736 = 176,640 f32
    ushort* qh = (ushort*)(ws + 176640);       // 8*32*768 = 196,608 ushort
    ushort* ql = (ushort*)(ws + 176640 + 98304);

    skl_normq<<<64, 256, 0, stream>>>(qe, qh, ql);
    skl_fused<<<dim3(NWCH, BB), 256, 0, stream>>>(de, qh, ql, dmask, qmask, qidfs,
                                                  mu, sigma, w1, b1, w2, b2, w3, b3,
                                                  dw, pscore);
    skl_topk<<<BB, 256, 0, stream>>>(pscore, chunk, out);
}

// Round 11
// 42.711 us; speedup vs baseline: 1.4372x; 1.4372x over previous
//
#include <hip/hip_runtime.h>

// Problem constants (from reference setup_inputs)
#define BB 8
#define QQ 30
#define DD 1500
#define EE 768
#define KK 11
#define WW 736      // (1500-30)/2 + 1
#define WIN 30
#define STR 2

#define NT 94       // n-tiles of 16 d (94*16 = 1504 >= 1500)

typedef __attribute__((ext_vector_type(8))) __bf16 bf16x8;
typedef __attribute__((ext_vector_type(4))) float f32x4;
typedef __attribute__((ext_vector_type(4))) unsigned int uint4v;

__device__ inline unsigned int f2bf(float x) {   // f32 -> bf16 bits, RNE
    unsigned int u = __float_as_uint(x);
    return (u + 0x7fffu + ((u >> 16) & 1u)) >> 16;
}

__device__ inline void split8(const float4 va, const float4 vb,
                              bf16x8& bh, bf16x8& bl, float& ssq)
{
    float f[8] = {va.x, va.y, va.z, va.w, vb.x, vb.y, vb.z, vb.w};
    unsigned hu[8], lu[8];
    #pragma unroll
    for (int j = 0; j < 8; j++) {
        float x = f[j];
        ssq += x * x;
        unsigned h = f2bf(x);
        float hf = __uint_as_float(h << 16);
        unsigned l = f2bf(x - hf);
        hu[j] = h; lu[j] = l;
    }
    uint4v uh = {hu[0] | (hu[1] << 16), hu[2] | (hu[3] << 16),
                 hu[4] | (hu[5] << 16), hu[6] | (hu[7] << 16)};
    uint4v ul = {lu[0] | (lu[1] << 16), lu[2] | (lu[3] << 16),
                 lu[4] | (lu[5] << 16), lu[6] | (lu[7] << 16)};
    bh = __builtin_bit_cast(bf16x8, uh);
    bl = __builtin_bit_cast(bf16x8, ul);
}

#define MFMA(a, b, c) __builtin_amdgcn_mfma_f32_16x16x32_bf16(a, b, c, 0, 0, 0)

// ---------------------------------------------------------------------------
// Kernel 1: normalize q rows, split to bf16 hi/lo, pad to 32 rows (zeros)
// ---------------------------------------------------------------------------
__global__ __launch_bounds__(256) void skl_normq(
    const float* __restrict__ qe, ushort* __restrict__ qh, ushort* __restrict__ ql)
{
    int wid = threadIdx.x >> 6, lane = threadIdx.x & 63;
    int r = blockIdx.x * 4 + wid;        // 0..255 = b*32+q
    if (r >= BB * 32) return;
    int b = r >> 5, q = r & 31;
    ushort* ph = qh + (size_t)r * EE;
    ushort* pl = ql + (size_t)r * EE;
    if (q >= QQ) {
        #pragma unroll
        for (int k = 0; k < 3; k++) {
            int e = (lane + 64 * k) * 4;
            *(ushort4*)&ph[e] = make_ushort4(0, 0, 0, 0);
            *(ushort4*)&pl[e] = make_ushort4(0, 0, 0, 0);
        }
        return;
    }
    const float4* p = (const float4*)(qe + (size_t)(b * QQ + q) * EE);
    float4 v[3];
    float ss = 0.f;
    #pragma unroll
    for (int k = 0; k < 3; k++) {
        v[k] = p[lane + 64 * k];
        ss += v[k].x * v[k].x + v[k].y * v[k].y + v[k].z * v[k].z + v[k].w * v[k].w;
    }
    #pragma unroll
    for (int off = 32; off >= 1; off >>= 1) ss += __shfl_xor(ss, off);
    float inv = 1.f / fmaxf(sqrtf(ss), 1e-13f);
    #pragma unroll
    for (int k = 0; k < 3; k++) {
        float f[4] = {v[k].x * inv, v[k].y * inv, v[k].z * inv, v[k].w * inv};
        ushort hs[4], ls[4];
        #pragma unroll
        for (int j = 0; j < 4; j++) {
            unsigned h = f2bf(f[j]);
            float hf = __uint_as_float(h << 16);
            unsigned l = f2bf(f[j] - hf);
            hs[j] = (ushort)h; ls[j] = (ushort)l;
        }
        int e = (lane + 64 * k) * 4;
        *(ushort4*)&ph[e] = make_ushort4(hs[0], hs[1], hs[2], hs[3]);
        *(ushort4*)&pl[e] = make_ushort4(ls[0], ls[1], ls[2], ls[3]);
    }
}

// ---------------------------------------------------------------------------
// Kernel 2 (v7): split-bf16 MFMA GEMM, FULL K per block via wave-K-split.
// Block: 16 d x 30 q x K=768; wave w handles K-range [192w, 192w+192).
// LDS reduce (10KB) sums 4 wave-partials + ssq; invd applied in-block;
// writes FINAL normalized cosine (no partial round-trips).
// grid = (94 n-tiles, 8 batches) = 752 blocks ~ 2.94/CU.
// ---------------------------------------------------------------------------
__global__ __launch_bounds__(256) void skl_gemm(
    const float* __restrict__ de,      // [8][1500][768] f32
    const ushort* __restrict__ qh,     // [8][32][768] bf16 bits
    const ushort* __restrict__ ql,
    float* __restrict__ cosm)          // [8][30][1500] final cosine
{
    __shared__ float red[4][64][10];   // [wave][lane][acc0(4),acc1(4),ssq,pad]
    int tid = threadIdx.x;
    int wave = tid >> 6, lane = tid & 63;
    int ln = lane & 15, g = lane >> 4;
    int nt = blockIdx.x, b = blockIdx.y;
    int d = nt * 16 + ln;
    int dc = min(d, DD - 1);
    const float* drow = de + ((size_t)b * DD + dc) * EE;
    const ushort* qhb = qh + (size_t)b * 32 * EE;
    const ushort* qlb = ql + (size_t)b * 32 * EE;

    f32x4 acc0 = {0.f, 0.f, 0.f, 0.f};
    f32x4 acc1 = {0.f, 0.f, 0.f, 0.f};
    float ssq = 0.f;
    int k0 = wave * 192;

    #pragma unroll
    for (int kst = 0; kst < 6; kst++) {
        int e0 = k0 + kst * 32 + 8 * g;
        bf16x8 a0h = *(const bf16x8*)&qhb[(size_t)ln * EE + e0];
        bf16x8 a0l = *(const bf16x8*)&qlb[(size_t)ln * EE + e0];
        bf16x8 a1h = *(const bf16x8*)&qhb[(size_t)(16 + ln) * EE + e0];
        bf16x8 a1l = *(const bf16x8*)&qlb[(size_t)(16 + ln) * EE + e0];
        float4 va = *(const float4*)&drow[e0];
        float4 vb = *(const float4*)&drow[e0 + 4];
        bf16x8 bh, bl;
        split8(va, vb, bh, bl, ssq);
        acc0 = MFMA(a0h, bh, acc0);
        acc0 = MFMA(a0h, bl, acc0);
        acc0 = MFMA(a0l, bh, acc0);
        acc1 = MFMA(a1h, bh, acc1);
        acc1 = MFMA(a1h, bl, acc1);
        acc1 = MFMA(a1l, bh, acc1);
    }

    // per-wave ssq for d=ln over this wave's K-range (sum the 4 g-groups)
    ssq += __shfl_xor(ssq, 16);
    ssq += __shfl_xor(ssq, 32);

    #pragma unroll
    for (int j = 0; j < 4; j++) {
        red[wave][lane][j] = acc0[j];
        red[wave][lane][4 + j] = acc1[j];
    }
    red[wave][lane][8] = ssq;
    __syncthreads();

    if (wave == 0) {
        float a0f[4] = {0.f, 0.f, 0.f, 0.f};
        float a1f[4] = {0.f, 0.f, 0.f, 0.f};
        float sf = 0.f;
        #pragma unroll
        for (int w = 0; w < 4; w++) {
            #pragma unroll
            for (int j = 0; j < 4; j++) {
                a0f[j] += red[w][lane][j];
                a1f[j] += red[w][lane][4 + j];
            }
            sf += red[w][lane][8];
        }
        float inv = 1.f / fmaxf(sqrtf(sf), 1e-13f);
        if (d < DD) {
            #pragma unroll
            for (int j = 0; j < 4; j++) {
                int q0 = 4 * g + j;           // C row = 4g+j, col = ln
                cosm[((size_t)b * QQ + q0) * DD + d] = a0f[j] * inv;
                int q1 = 16 + q0;
                if (q1 < QQ)
                    cosm[((size_t)b * QQ + q1) * DD + d] = a1f[j] * inv;
            }
        }
    }
}

// ---------------------------------------------------------------------------
// Kernel 3: RBF (f32 __expf) -> window sums (f32, float2 LDS reads) ->
// saturation (f32 fast pow) -> dense_w. Block per (b,q,chunk of 256 windows).
// ---------------------------------------------------------------------------
#define DCH 544    // max d-extent a chunk needs (2*255+29+1 = 540, padded)

__global__ __launch_bounds__(256) void skl_windows(
    const float* __restrict__ cosm,    // [8][30][1500] final cosine
    const float* __restrict__ dmask,   // [8][1500]
    const float* __restrict__ qmask,   // [8][30]
    const float* __restrict__ qidfs,   // [240]
    const float* __restrict__ mu,      // [11]
    const float* __restrict__ sigma,   // [11]
    const float* __restrict__ w1, const float* __restrict__ b1,
    const float* __restrict__ w2, const float* __restrict__ b2,
    const float* __restrict__ w3, const float* __restrict__ b3,
    const float* __restrict__ dw,      // [11]
    float* __restrict__ pscore)        // [240][736]
{
    __shared__ float vf[KK][DCH];      // 23.9 KB
    __shared__ float fl[DCH];          // 2.2 KB

    int bid = blockIdx.x;     // 0..719
    int c  = bid % 3;
    int bq = bid / 3;         // 0..239
    int b  = bq / QQ;
    int tid = threadIdx.x;

    int dbase = 512 * c;
    int dcount = min(540, DD - dbase);
    int w = c * 256 + tid;
    bool active = (w < WW);

    float muL[KK], i2s[KK], dwL[KK];
    #pragma unroll
    for (int k = 0; k < KK; k++) {
        muL[k] = mu[k];
        float s = sigma[k];
        i2s[k] = 1.f / (2.f * s * s);
        dwL[k] = dw[k];
    }
    const float* dm = dmask + (size_t)b * DD + dbase;
    const float* crow = cosm + (size_t)bq * DD + dbase;

    // phase 1: 11 RBF values per d
    for (int i = tid; i < dcount; i += 256) {
        float cc = crow[i];
        float m = dm[i];
        float ssum = 0.f;
        #pragma unroll
        for (int k = 0; k < KK; k++) {
            float diff = cc - muL[k];
            float val = __expf(-diff * diff * i2s[k]) * m;
            ssum += val;
            vf[k][i] = val;
        }
        fl[i] = (ssum != 0.f) ? 1.f : 0.f;
    }
    __syncthreads();

    // phase 2: per-window sums + saturation + dense_w
    if (active) {
        int dl = 2 * tid;     // window covers d-pairs tid..tid+14 (8B-aligned)
        float pk[KK];
        #pragma unroll
        for (int k = 0; k < KK; k++) pk[k] = 0.f;
        float lenf = 0.f;
        #pragma unroll
        for (int j2 = 0; j2 < WIN / 2; j2++) {
            float2 f2 = *(const float2*)&fl[dl + 2 * j2];
            lenf += f2.x + f2.y;
            #pragma unroll
            for (int k = 0; k < KK; k++) {
                float2 v2 = *(const float2*)&vf[k][dl + 2 * j2];
                pk[k] += v2.x + v2.y;
            }
        }
        float idf = fmaxf(qidfs[bq], 0.f);
        float sat1 = idf * w1[0] + lenf * w1[1] + b1[0];
        float sat2 = 1.f / (idf * w2[0] + lenf * w2[1] + b2[0]);
        float sat3 = idf * w3[0] + lenf * w3[1] + b3[0];
        float mult = qmask[bq] * (lenf > 0.f ? 1.f : 0.f);

        float acc = 0.f;
        #pragma unroll
        for (int k = 0; k < KK; k++) {
            float x = fmaxf(pk[k], 1e-10f);
            float p = exp2f(sat2 * __log2f(x));
            acc += (sat1 * p - sat3) * dwL[k];
        }
        pscore[(size_t)bq * WW + w] = acc * mult;
    }
}

// ---------------------------------------------------------------------------
// Kernel 4: per batch: sum over q (256 threads), then single-wave top-3
// argmax + pooling + gather.
// ---------------------------------------------------------------------------
__global__ __launch_bounds__(256) void skl_topk(
    const float* __restrict__ pscore,  // [240][736]
    const float* __restrict__ chunk,   // [15]
    float* __restrict__ out)           // [8]
{
    __shared__ float s0[WW];
    int b = blockIdx.x;
    int tid = threadIdx.x;

    for (int w = tid; w < WW; w += 256) {
        float s = 0.f;
        for (int q = 0; q < QQ; q++) s += pscore[(size_t)(b * QQ + q) * WW + w];
        s0[w] = (s == 0.f) ? -9900.f : s;
    }
    __syncthreads();

    if (tid < 64) {
        int lane = tid;
        float m[12];
        #pragma unroll
        for (int r = 0; r < 12; r++) {
            int w = lane + 64 * r;
            m[r] = (w < WW) ? s0[w] : -3.3e38f;
        }

        int best[3];
        for (int c = 0; c < 3; c++) {
            float bv = -3.3e38f;
            int bi = 1 << 30;
            #pragma unroll
            for (int r = 0; r < 12; r++) {
                int w = lane + 64 * r;
                if (w < WW && m[r] > bv) { bv = m[r]; bi = w; }
            }
            #pragma unroll
            for (int off = 32; off >= 1; off >>= 1) {
                float ov = __shfl_down(bv, off);
                int oi = __shfl_down(bi, off);
                if (ov > bv || (ov == bv && oi < bi)) { bv = ov; bi = oi; }
            }
            bi = __shfl(bi, 0);
            best[c] = bi;
            float pen = -10001.f - (float)c;
            #pragma unroll
            for (int r = 0; r < 12; r++) {
                int w = lane + 64 * r;
                int dd = w - bi; if (dd < 0) dd = -dd;
                if (w < WW && dd < 15) m[r] = pen;
            }
        }

        float contrib = 0.f;
        if (lane < 15) {
            int c = lane % 3;
            int g = lane / 3;
            const int offs[5] = {0, -1, 1, -2, 2};
            int nb = best[c] + offs[g];
            nb = min(max(nb, 0), WW - 1);
            float v = s0[nb];
            if (v <= -9900.f) v = 0.f;
            contrib = v * chunk[lane];
        }
        #pragma unroll
        for (int off = 32; off >= 1; off >>= 1) contrib += __shfl_down(contrib, off);
        if (lane == 0) out[b] = contrib;
    }
}

// ---------------------------------------------------------------------------
extern "C" void kernel_launch(void* const* d_in, const int* in_sizes, int n_in,
                              void* d_out, int out_size, void* d_ws, size_t ws_size,
                              hipStream_t stream) {
    const float* qe    = (const float*)d_in[0];   // (8,30,768)
    const float* de    = (const float*)d_in[1];   // (8,1500,768)
    const float* qmask = (const float*)d_in[2];   // (8,30)
    const float* dmask = (const float*)d_in[3];   // (8,1500)
    const float* qidfs = (const float*)d_in[4];   // (8,30,1)
    // d_in[5] = document_idfs (unused by reference)
    const float* mu    = (const float*)d_in[6];   // (11,)
    const float* sigma = (const float*)d_in[7];   // (11,)
    const float* w1    = (const float*)d_in[8];
    const float* b1    = (const float*)d_in[9];
    const float* w2    = (const float*)d_in[10];
    const float* b2    = (const float*)d_in[11];
    const float* w3    = (const float*)d_in[12];
    const float* b3    = (const float*)d_in[13];
    const float* dw    = (const float*)d_in[14];  // (1,11)
    const float* chunk = (const float*)d_in[15];  // (1,15)
    float* out = (float*)d_out;

    float* ws = (float*)d_ws;
    float* cosm   = ws;                        // 240*1500 = 360,000 f32
    float* pscore = ws + 360000;               // 240*736  = 176,640 f32
    ushort* qh = (ushort*)(ws + 536640);       // 8*32*768 = 196,608 ushort
    ushort* ql = (ushort*)(ws + 536640 + 98304);   // (~2.9MB total)

    skl_normq<<<64, 256, 0, stream>>>(qe, qh, ql);
    skl_gemm<<<dim3(NT, BB), 256, 0, stream>>>(de, qh, ql, cosm);
    skl_windows<<<BB * QQ * 3, 256, 0, stream>>>(cosm, dmask, qmask, qidfs,
                                                 mu, sigma, w1, b1, w2, b2, w3, b3,
                                                 dw, pscore);
    skl_topk<<<BB, 256, 0, stream>>>(pscore, chunk, out);
}